// Round 6
// baseline (11235.647 us; speedup 1.0000x reference)
//
#include <hip/hip_runtime.h>
#include <hip/hip_bf16.h>

// RITS recurrent imputation, B=1024 T=100 F=64 H=256.
// Round 6: 4-way N-split of the LSTM gates GEMM across sibling blocks.
// Grid 256 = 64 groups x 4 siblings = all 256 CUs (1 block/CU forced by
// LDS ~120KB and 16 waves x 128 VGPR). Sibling j owns H-cols [64j,64j+64):
// its gate weights live in REGISTERS (12 x short8 = 48 VGPR/wave) for the
// whole kernel -> zero steady-state weight traffic. Small weights LDS-resident.
// Per step: one cross-sibling h-exchange via workspace + device-scope
// release/acquire counter (cumulative, zeroed each launch by convert).

#define Bz 1024
#define Tz 100
#define Fz 64
#define Hz 256
#define GROUPS 64
#define SIBS 4
#define RPB 16

typedef __attribute__((ext_vector_type(8))) short short8;
typedef __attribute__((ext_vector_type(4))) float floatx4;
typedef __hip_bfloat16 bf16;

#define MFMA16(a, b, c) __builtin_amdgcn_mfma_f32_16x16x32_bf16((a), (b), (c), 0, 0, 0)

__device__ __forceinline__ float sigmf(float x) { return 1.0f / (1.0f + __expf(-x)); }
__device__ __forceinline__ float tanhfast(float x) { return 2.0f / (1.0f + __expf(-2.0f * x)) - 1.0f; }

// ws layout (bytes):
//   wsbf (bf16): Wdh[256x64]@0, Whist[64x256]@16384, Wfeatm[64x64]@32768,
//     Wcomb[64x128]@36864, Wp5[12*32768]@45056 ; 438272 bf16 = 876544 B
//   @876544: wdx_diag[64] f32
//   @876800: lossbuf[64*100*4] f32 (102400 B)
//   @979200: cnt[64] u32 (256 B)
//   @979456: pub[64][16][256] bf16 (524288 B)
// Wp5 flat: s*32768 + w5*2048 + g*512 + l*32 + q*8 + e ; row n=g*256+w5*16+l;
// s<4 -> Wih[n][s*32+q*8+e], s>=4 -> Whh[n][(s-4)*32+q*8+e].

__global__ void rits_convert(const float* __restrict__ Wdh, const float* __restrict__ Wdx,
                             const float* __restrict__ Whist, const float* __restrict__ Wfeat,
                             const float* __restrict__ Wcomb, const float* __restrict__ Wih,
                             const float* __restrict__ Whh, bf16* __restrict__ wsbf,
                             float* __restrict__ wdxd, unsigned int* __restrict__ cnt) {
    int idx = blockIdx.x * blockDim.x + threadIdx.x;
    if (blockIdx.x == 0 && threadIdx.x < GROUPS) cnt[threadIdx.x] = 0u;
    if (idx < 64) wdxd[idx] = Wdx[idx * 65];  // diag of W_dx
    if (idx >= 438272) return;
    float v;
    if (idx < 16384) v = Wdh[idx];
    else if (idx < 32768) v = Whist[idx - 16384];
    else if (idx < 36864) { int i = idx - 32768; v = ((i >> 6) == (i & 63)) ? 0.0f : Wfeat[i]; }
    else if (idx < 45056) v = Wcomb[idx - 36864];
    else {
        int i = idx - 45056;
        int e = i & 7, q = (i >> 3) & 3, l = (i >> 5) & 15, g = (i >> 9) & 3, w = (i >> 11) & 15;
        int s = i >> 15;
        int n = g * 256 + w * 16 + l;
        v = (s < 4) ? Wih[n * 128 + s * 32 + q * 8 + e] : Whh[n * 256 + (s - 4) * 32 + q * 8 + e];
    }
    wsbf[idx] = __float2bfloat16(v);
}

__global__ __launch_bounds__(1024, 4) void rits_main(
    const float* __restrict__ X, const float* __restrict__ Mm, const float* __restrict__ Dd,
    const float* __restrict__ b_dh, const float* __restrict__ b_dx,
    const float* __restrict__ b_hist, const float* __restrict__ b_feat,
    const float* __restrict__ b_comb, const float* __restrict__ b_ih,
    const float* __restrict__ b_hh,
    const bf16* __restrict__ Wdh, const bf16* __restrict__ Whist,
    const bf16* __restrict__ Wfeatm, const bf16* __restrict__ Wcomb,
    const bf16* __restrict__ Wp5,
    const float* __restrict__ wdxd, float* __restrict__ lossbuf,
    unsigned int* __restrict__ cnt, bf16* __restrict__ pub, float* __restrict__ out) {
    // ---- LDS (~121 KB -> exactly 1 block/CU) ----
    __shared__ __align__(16) bf16 lw_hist[64 * 264];  // Whist rows padded
    __shared__ __align__(16) bf16 lw_comb[64 * 136];
    __shared__ __align__(16) bf16 lw_feat[64 * 72];
    __shared__ __align__(16) bf16 lw_dh[64 * 72];     // local 64 rows of Wdh
    __shared__ __align__(16) bf16 sh_hbf[RPB * 264];  // full decayed h (bf16)
    __shared__ __align__(16) float sh_x[RPB * 64];
    __shared__ __align__(16) float sh_m[RPB * 64];
    __shared__ __align__(16) bf16 sh_dbf[RPB * 72];
    __shared__ __align__(16) bf16 sh_xcbf[RPB * 72];
    __shared__ __align__(16) bf16 sh_gmbf[RPB * 136];
    __shared__ __align__(16) bf16 sh_inbf[RPB * 136];
    __shared__ __align__(16) float sh_g[4 * 16 * 66];   // post-nonlin gates (local cols)
    __shared__ __align__(16) float sh_hloc[16 * 66];    // fp32 h (local cols)
    __shared__ float sh_lred[16];
    __shared__ float sh_msum[16];

    const int tid = threadIdx.x;
    const int lane = tid & 63;
    const int wid = tid >> 6;   // 0..15
    const int l16 = lane & 15;
    const int q = lane >> 4;    // 0..3
    const int j = blockIdx.x & 3;         // sibling: owns H cols [64j, 64j+64)
    const int grp = blockIdx.x >> 2;      // group 0..63
    const int b0 = grp * RPB;

    // ---- one-time LDS copy-in of small weights ----
    for (int i = tid; i < 64 * 256; i += 1024) lw_hist[(i >> 8) * 264 + (i & 255)] = Whist[i];
    for (int i = tid; i < 64 * 128; i += 1024) lw_comb[(i >> 7) * 136 + (i & 127)] = Wcomb[i];
    for (int i = tid; i < 64 * 64; i += 1024) {
        lw_feat[(i >> 6) * 72 + (i & 63)] = Wfeatm[i];
        lw_dh[(i >> 6) * 72 + (i & 63)] = Wdh[(j * 64 + (i >> 6)) * 64 + (i & 63)];
    }
    for (int i = tid; i < 16 * 66; i += 1024) sh_hloc[i] = 0.0f;

    // ---- P5 gate-weight fragments: PERMANENT register residency ----
    const int gate = wid >> 2;   // 0..3 (i,f,g,o)
    const int ct = wid & 3;      // col-tile within sibling slice
    const int nrow = gate * 256 + j * 64 + ct * 16 + l16;  // global gate row
    short8 wfrag[12];
#pragma unroll
    for (int s = 0; s < 12; ++s)
        wfrag[s] = *(const short8*)(Wp5 + (size_t)s * 32768 + (j * 4 + ct) * 2048 + gate * 512 +
                                    l16 * 32 + q * 8);
    const float bgate = b_ih[nrow] + b_hh[nrow];

    // ---- other step-invariant scalars ----
    const int colF = wid * 16 + l16;           // F col (waves 0-3, P2/P34)
    const int gcolH = j * 64 + colF;           // global H col (waves 0-3, P1)
    const float wdxf = wdxd[lane];
    const float bdxf = b_dx[lane];
    float bdl = 0.f, bhl = 0.f, bft = 0.f, bcl = 0.f;
    if (wid < 4) { bdl = b_dh[gcolH]; bhl = b_hist[colF]; bft = b_feat[colF]; bcl = b_comb[colF]; }

    float creg = 0.0f;  // c state: element (row=tid>>6, lcol=tid&63)

    // input prefetch (row = wid, f = lane)
    const size_t g0 = (size_t)(b0 + wid) * Tz * Fz + lane;
    float xv = X[g0], mv = Mm[g0], dv = Dd[g0];

    bf16* pubg = pub + (size_t)grp * (16 * 256);
    __syncthreads();

    for (int t = 0; t < Tz; ++t) {
        // ---- P0: stage inputs; gamma_x; m halves; mask-sum ----
        {
            const int row = wid, f = lane;
            sh_x[row * 64 + f] = xv;
            sh_m[row * 64 + f] = mv;
            float gx = __expf(-fmaxf(dv * wdxf + bdxf, 0.0f));
            sh_gmbf[row * 136 + f] = __float2bfloat16(gx);
            bf16 mb = __float2bfloat16(mv);
            sh_gmbf[row * 136 + 64 + f] = mb;
            sh_inbf[row * 136 + 64 + f] = mb;
            sh_dbf[row * 72 + f] = __float2bfloat16(dv);
            float v0 = mv;
#pragma unroll
            for (int off = 32; off; off >>= 1) v0 += __shfl_xor(v0, off, 64);
            if (lane == 0) sh_msum[wid] = v0;
        }
        __syncthreads();  // bar A

        // ---- P1: gamma_h for OWN 64 cols; decay; publish bf16 slice ----
        if (wid < 4) {
            short8 a0 = *(const short8*)(sh_dbf + l16 * 72 + q * 8);
            short8 a1 = *(const short8*)(sh_dbf + l16 * 72 + 32 + q * 8);
            short8 w0 = *(const short8*)(lw_dh + colF * 72 + q * 8);
            short8 w1 = *(const short8*)(lw_dh + colF * 72 + 32 + q * 8);
            floatx4 acc = {0.f, 0.f, 0.f, 0.f};
            acc = MFMA16(a0, w0, acc);
            acc = MFMA16(a1, w1, acc);
#pragma unroll
            for (int r = 0; r < 4; ++r) {
                int row = q * 4 + r;
                float g = __expf(-fmaxf(acc[r] + bdl, 0.0f));
                float hn = sh_hloc[row * 66 + colF] * g;
                pubg[row * 256 + gcolH] = __float2bfloat16(hn);
            }
        }
        __syncthreads();  // bar B (drains publish stores: vmcnt(0))

        // ---- cross-sibling barrier: release-add, acquire-spin to 4(t+1) ----
        if (tid == 0) {
            __threadfence();
            __hip_atomic_fetch_add(cnt + grp, 1u, __ATOMIC_RELEASE, __HIP_MEMORY_SCOPE_AGENT);
            const unsigned int target = 4u * (unsigned int)(t + 1);
            while (__hip_atomic_load(cnt + grp, __ATOMIC_ACQUIRE, __HIP_MEMORY_SCOPE_AGENT) <
                   target)
                __builtin_amdgcn_s_sleep(2);
        }
        __syncthreads();  // bar C
        __threadfence();  // per-wave acquire: invalidate L1 for pub reads

        // ---- reload full decayed h (16x256 bf16) into sh_hbf ----
        {
            int row = tid >> 6, c4 = (tid & 63) * 4;
            uint2 v = *(const uint2*)(pubg + row * 256 + c4);
            *(uint2*)(sh_hbf + row * 264 + c4) = v;
        }
        __syncthreads();  // bar D

        // ---- P2: x_h = h@Whist^T + b (waves 0-3, LDS weights) ----
        float xh[4];
        float l1 = 0.f, l2 = 0.f, l3 = 0.f;
        if (wid < 4) {
            floatx4 acc = {0.f, 0.f, 0.f, 0.f};
#pragma unroll
            for (int kb = 0; kb < 8; ++kb) {
                short8 a = *(const short8*)(sh_hbf + l16 * 264 + kb * 32 + q * 8);
                short8 b = *(const short8*)(lw_hist + colF * 264 + kb * 32 + q * 8);
                acc = MFMA16(a, b, acc);
            }
#pragma unroll
            for (int r = 0; r < 4; ++r) {
                int row = q * 4 + r;
                xh[r] = acc[r] + bhl;
                float xx = sh_x[row * 64 + colF], mm = sh_m[row * 64 + colF];
                l1 += fabsf(xh[r] - xx) * mm;
                float xc = mm * xx + (1.0f - mm) * xh[r];
                sh_xcbf[row * 72 + colF] = __float2bfloat16(xc);
            }
        }
        __syncthreads();  // bar E

        // ---- P34: z_h, alpha, c_h, imputed (sibling 0 writes out), c_c ----
        if (wid < 4) {
            floatx4 accz = {0.f, 0.f, 0.f, 0.f};
            {
                short8 a = *(const short8*)(sh_xcbf + l16 * 72 + q * 8);
                accz = MFMA16(a, *(const short8*)(lw_feat + colF * 72 + q * 8), accz);
                a = *(const short8*)(sh_xcbf + l16 * 72 + 32 + q * 8);
                accz = MFMA16(a, *(const short8*)(lw_feat + colF * 72 + 32 + q * 8), accz);
            }
            floatx4 acca = {0.f, 0.f, 0.f, 0.f};
#pragma unroll
            for (int kb = 0; kb < 4; ++kb) {
                short8 a = *(const short8*)(sh_gmbf + l16 * 136 + kb * 32 + q * 8);
                short8 b = *(const short8*)(lw_comb + colF * 136 + kb * 32 + q * 8);
                acca = MFMA16(a, b, acca);
            }
#pragma unroll
            for (int r = 0; r < 4; ++r) {
                int row = q * 4 + r;
                float xx = sh_x[row * 64 + colF], mm = sh_m[row * 64 + colF];
                float z = accz[r] + bft;
                l2 += fabsf(z - xx) * mm;
                float al = sigmf(acca[r] + bcl);
                float ch = al * z + (1.0f - al) * xh[r];
                l3 += fabsf(ch - xx) * mm;
                float imp = mm * xx + (1.0f - mm) * ch;  // == c_c
                if (j == 0) out[((size_t)(b0 + row) * Tz + t) * Fz + colF] = imp;
                sh_inbf[row * 136 + colF] = __float2bfloat16(imp);
            }
            float v1 = l1, v2 = l2, v3 = l3;
#pragma unroll
            for (int off = 32; off; off >>= 1) {
                v1 += __shfl_xor(v1, off, 64);
                v2 += __shfl_xor(v2, off, 64);
                v3 += __shfl_xor(v3, off, 64);
            }
            if (lane == 0) {
                sh_lred[wid * 4 + 0] = v1;
                sh_lred[wid * 4 + 1] = v2;
                sh_lred[wid * 4 + 2] = v3;
            }
        }
        __syncthreads();  // bar F

        // ---- P5: gates slice from REGISTER weights (12 MFMAs/wave) ----
        {
            floatx4 acc = {0.f, 0.f, 0.f, 0.f};
#pragma unroll
            for (int s = 0; s < 12; ++s) {
                short8 a = (s < 4) ? *(const short8*)(sh_inbf + l16 * 136 + s * 32 + q * 8)
                                   : *(const short8*)(sh_hbf + l16 * 264 + (s - 4) * 32 + q * 8);
                acc = MFMA16(a, wfrag[s], acc);
            }
#pragma unroll
            for (int r = 0; r < 4; ++r) {
                float v = acc[r] + bgate;
                float tv = (gate == 2) ? tanhfast(v) : sigmf(v);
                sh_g[(gate * 16 + q * 4 + r) * 66 + ct * 16 + l16] = tv;
            }
        }
        __syncthreads();  // bar G

        // ---- LSTM elementwise: 1 element/thread; loss write; prefetch ----
        {
            int row = tid >> 6, lcol = tid & 63;
            float Ig = sh_g[(0 * 16 + row) * 66 + lcol];
            float Fg = sh_g[(1 * 16 + row) * 66 + lcol];
            float Gg = sh_g[(2 * 16 + row) * 66 + lcol];
            float Og = sh_g[(3 * 16 + row) * 66 + lcol];
            creg = Fg * creg + Ig * Gg;
            sh_hloc[row * 66 + lcol] = Og * tanhfast(creg);
        }
        if (j == 0 && tid == 0) {
            float s0 = 0.0f;
#pragma unroll
            for (int i = 0; i < 16; ++i) s0 += sh_msum[i];
            float* lb = lossbuf + ((size_t)grp * Tz + t) * 4;
            lb[0] = s0;
            lb[1] = sh_lred[0] + sh_lred[4] + sh_lred[8] + sh_lred[12];
            lb[2] = sh_lred[1] + sh_lred[5] + sh_lred[9] + sh_lred[13];
            lb[3] = sh_lred[2] + sh_lred[6] + sh_lred[10] + sh_lred[14];
        }
        if (t + 1 < Tz) {
            size_t g = g0 + (size_t)(t + 1) * Fz;
            xv = X[g]; mv = Mm[g]; dv = Dd[g];
        }
        __syncthreads();  // bar H (sh_msum/lred/hloc safe for next step)
    }
}

__global__ void rits_finalize(const float* __restrict__ lossbuf, float* __restrict__ out) {
    __shared__ float m1[Tz], m2[Tz], m3[Tz];
    int t = threadIdx.x;
    if (t < Tz) {
        float s0 = 0.0f, s1 = 0.0f, s2 = 0.0f, s3 = 0.0f;
        for (int g = 0; g < GROUPS; ++g) {
            const float* lb = lossbuf + ((size_t)g * Tz + t) * 4;
            s0 += lb[0]; s1 += lb[1]; s2 += lb[2]; s3 += lb[3];
        }
        float inv = 1.0f / (s0 + 1e-9f);
        m1[t] = s1 * inv; m2[t] = s2 * inv; m3[t] = s3 * inv;
    }
    __syncthreads();
    if (t == 0) {
        float rm = 0.0f, rl = 0.0f;
        for (int i = 0; i < Tz; ++i) {  // literal replay of reference accumulation
            rl += m1[i]; rl += m2[i]; rm += m3[i]; rl += rm;
        }
        out[(size_t)Bz * Tz * Fz] = rm / (float)Tz;
        out[(size_t)Bz * Tz * Fz + 1] = rl / (3.0f * (float)Tz);
    }
}

extern "C" void kernel_launch(void* const* d_in, const int* in_sizes, int n_in,
                              void* d_out, int out_size, void* d_ws, size_t ws_size,
                              hipStream_t stream) {
    const float* X = (const float*)d_in[0];
    const float* Mm = (const float*)d_in[1];
    const float* Dd = (const float*)d_in[2];
    const float* Wdh = (const float*)d_in[3];
    const float* b_dh = (const float*)d_in[4];
    const float* Wdx = (const float*)d_in[5];
    const float* b_dx = (const float*)d_in[6];
    const float* Whist = (const float*)d_in[7];
    const float* b_hist = (const float*)d_in[8];
    const float* Wfeat = (const float*)d_in[9];
    const float* b_feat = (const float*)d_in[10];
    const float* Wcomb = (const float*)d_in[11];
    const float* b_comb = (const float*)d_in[12];
    const float* Wih = (const float*)d_in[13];
    const float* b_ih = (const float*)d_in[14];
    const float* Whh = (const float*)d_in[15];
    const float* b_hh = (const float*)d_in[16];
    float* out = (float*)d_out;

    bf16* wsbf = (bf16*)d_ws;
    float* wdxd = (float*)((char*)d_ws + 876544);
    float* lossbuf = (float*)((char*)d_ws + 876800);
    unsigned int* cnt = (unsigned int*)((char*)d_ws + 979200);
    bf16* pub = (bf16*)((char*)d_ws + 979456);

    rits_convert<<<1712, 256, 0, stream>>>(Wdh, Wdx, Whist, Wfeat, Wcomb, Wih, Whh, wsbf, wdxd,
                                           cnt);
    rits_main<<<GROUPS * SIBS, 1024, 0, stream>>>(
        X, Mm, Dd, b_dh, b_dx, b_hist, b_feat, b_comb, b_ih, b_hh, wsbf + 0, wsbf + 16384,
        wsbf + 32768, wsbf + 36864, wsbf + 45056, wdxd, lossbuf, cnt, pub, out);
    rits_finalize<<<1, 128, 0, stream>>>(lossbuf, out);
}

// Round 7
// 1530.550 us; speedup vs baseline: 7.3409x; 7.3409x over previous
//
#include <hip/hip_runtime.h>
#include <hip/hip_bf16.h>

// RITS recurrent imputation, B=1024 T=100 F=64 H=256.
// Round 7: R6's 4-way N-split (256 blocks = all CUs, LSTM gate weights
// PERMANENTLY register-resident, 12 MFMAs/wave/step) with FENCE-FREE
// cross-sibling h-exchange: relaxed device-scope atomic RMWs (LLC coherence
// point, no buffer_wbl2/inv), ordering via s_waitcnt vmcnt(0), cumulative
// flag counter, parity-double-buffered pub. R6's 85us/step sync cost was
// the acquire/release L2 writeback/invalidate — eliminated here.

#define Bz 1024
#define Tz 100
#define Fz 64
#define Hz 256
#define GROUPS 64
#define SIBS 4
#define RPB 16

typedef __attribute__((ext_vector_type(8))) short short8;
typedef __attribute__((ext_vector_type(4))) float floatx4;
typedef __hip_bfloat16 bf16;
typedef unsigned long long u64;

#define MFMA16(a, b, c) __builtin_amdgcn_mfma_f32_16x16x32_bf16((a), (b), (c), 0, 0, 0)

__device__ __forceinline__ float sigmf(float x) { return 1.0f / (1.0f + __expf(-x)); }
__device__ __forceinline__ float tanhfast(float x) { return 2.0f / (1.0f + __expf(-2.0f * x)) - 1.0f; }

// ws layout (bytes):
//   wsbf (bf16): Wdh[256x64]@0, Whist[64x256]@16384, Wfeatm[64x64]@32768,
//     Wcomb[64x128]@36864, Wp5[12*32768]@45056 ; 438272 bf16 = 876544 B
//   @876544: wdx_diag[64] f32
//   @876800: lossbuf[64*100*4] f32 (102400 B)
//   @979200: cnt[64] u32 (256 B)
//   @979456: pub[64][2][16][256] bf16 (1 MB) -- parity double buffer
// Wp5 flat: s*32768 + w5*2048 + g*512 + l*32 + q*8 + e ; row n=g*256+w5*16+l;
// s<4 -> Wih[n][s*32+q*8+e], s>=4 -> Whh[n][(s-4)*32+q*8+e].

__global__ void rits_convert(const float* __restrict__ Wdh, const float* __restrict__ Wdx,
                             const float* __restrict__ Whist, const float* __restrict__ Wfeat,
                             const float* __restrict__ Wcomb, const float* __restrict__ Wih,
                             const float* __restrict__ Whh, bf16* __restrict__ wsbf,
                             float* __restrict__ wdxd, unsigned int* __restrict__ cnt) {
    int idx = blockIdx.x * blockDim.x + threadIdx.x;
    if (blockIdx.x == 0 && threadIdx.x < GROUPS) cnt[threadIdx.x] = 0u;
    if (idx < 64) wdxd[idx] = Wdx[idx * 65];  // diag of W_dx
    if (idx >= 438272) return;
    float v;
    if (idx < 16384) v = Wdh[idx];
    else if (idx < 32768) v = Whist[idx - 16384];
    else if (idx < 36864) { int i = idx - 32768; v = ((i >> 6) == (i & 63)) ? 0.0f : Wfeat[i]; }
    else if (idx < 45056) v = Wcomb[idx - 36864];
    else {
        int i = idx - 45056;
        int e = i & 7, q = (i >> 3) & 3, l = (i >> 5) & 15, g = (i >> 9) & 3, w = (i >> 11) & 15;
        int s = i >> 15;
        int n = g * 256 + w * 16 + l;
        v = (s < 4) ? Wih[n * 128 + s * 32 + q * 8 + e] : Whh[n * 256 + (s - 4) * 32 + q * 8 + e];
    }
    wsbf[idx] = __float2bfloat16(v);
}

__global__ __launch_bounds__(1024, 4) void rits_main(
    const float* __restrict__ X, const float* __restrict__ Mm, const float* __restrict__ Dd,
    const float* __restrict__ b_dh, const float* __restrict__ b_dx,
    const float* __restrict__ b_hist, const float* __restrict__ b_feat,
    const float* __restrict__ b_comb, const float* __restrict__ b_ih,
    const float* __restrict__ b_hh,
    const bf16* __restrict__ Wdh, const bf16* __restrict__ Whist,
    const bf16* __restrict__ Wfeatm, const bf16* __restrict__ Wcomb,
    const bf16* __restrict__ Wp5,
    const float* __restrict__ wdxd, float* __restrict__ lossbuf,
    unsigned int* __restrict__ cnt, bf16* __restrict__ pub, float* __restrict__ out) {
    // ---- LDS (~113 KB -> 1 block/CU) ----
    __shared__ __align__(16) bf16 lw_hist[64 * 264];
    __shared__ __align__(16) bf16 lw_comb[64 * 136];
    __shared__ __align__(16) bf16 lw_feat[64 * 72];
    __shared__ __align__(16) bf16 lw_dh[64 * 72];
    __shared__ __align__(16) bf16 sh_hbf[RPB * 264];   // full decayed h (bf16)
    __shared__ __align__(16) bf16 sh_hpub[RPB * 68];   // own slice, publish staging
    __shared__ __align__(16) float sh_x[RPB * 64];
    __shared__ __align__(16) float sh_m[RPB * 64];
    __shared__ __align__(16) bf16 sh_dbf[RPB * 72];
    __shared__ __align__(16) bf16 sh_xcbf[RPB * 72];
    __shared__ __align__(16) bf16 sh_gmbf[RPB * 136];
    __shared__ __align__(16) bf16 sh_inbf[RPB * 136];
    __shared__ __align__(16) float sh_g[4 * 16 * 66];  // post-nonlin gates (local cols)
    __shared__ __align__(16) float sh_hloc[16 * 66];   // fp32 h (local cols)
    __shared__ float sh_lred[16];
    __shared__ float sh_msum[16];

    const int tid = threadIdx.x;
    const int lane = tid & 63;
    const int wid = tid >> 6;   // 0..15
    const int l16 = lane & 15;
    const int q = lane >> 4;    // 0..3
    const int j = blockIdx.x & 3;     // sibling: owns H cols [64j, 64j+64)
    const int grp = blockIdx.x >> 2;  // group 0..63
    const int b0 = grp * RPB;

    // ---- one-time LDS copy-in of small weights ----
    for (int i = tid; i < 64 * 256; i += 1024) lw_hist[(i >> 8) * 264 + (i & 255)] = Whist[i];
    for (int i = tid; i < 64 * 128; i += 1024) lw_comb[(i >> 7) * 136 + (i & 127)] = Wcomb[i];
    for (int i = tid; i < 64 * 64; i += 1024) {
        lw_feat[(i >> 6) * 72 + (i & 63)] = Wfeatm[i];
        lw_dh[(i >> 6) * 72 + (i & 63)] = Wdh[(j * 64 + (i >> 6)) * 64 + (i & 63)];
    }
    for (int i = tid; i < 16 * 66; i += 1024) sh_hloc[i] = 0.0f;

    // ---- P5 gate-weight fragments: PERMANENT register residency ----
    const int gate = wid >> 2;  // 0..3 (i,f,g,o)
    const int ct = wid & 3;     // col-tile within sibling slice
    const int nrow = gate * 256 + j * 64 + ct * 16 + l16;
    short8 wfrag[12];
#pragma unroll
    for (int s = 0; s < 12; ++s)
        wfrag[s] = *(const short8*)(Wp5 + (size_t)s * 32768 + (j * 4 + ct) * 2048 + gate * 512 +
                                    l16 * 32 + q * 8);
    const float bgate = b_ih[nrow] + b_hh[nrow];

    // ---- other step-invariant scalars ----
    const int colF = wid * 16 + l16;  // F col (waves 0-3)
    const int gcolH = j * 64 + colF;  // global H col (waves 0-3, P1)
    const float wdxf = wdxd[lane];
    const float bdxf = b_dx[lane];
    float bdl = 0.f, bhl = 0.f, bft = 0.f, bcl = 0.f;
    if (wid < 4) { bdl = b_dh[gcolH]; bhl = b_hist[colF]; bft = b_feat[colF]; bcl = b_comb[colF]; }

    float creg = 0.0f;  // c state: element (row=tid>>6, lcol=tid&63)

    // input prefetch (row = wid, f = lane)
    const size_t g0 = (size_t)(b0 + wid) * Tz * Fz + lane;
    float xv = X[g0], mv = Mm[g0], dv = Dd[g0];

    __syncthreads();

    for (int t = 0; t < Tz; ++t) {
        bf16* pubt = pub + ((size_t)grp * 2 + (t & 1)) * (16 * 256);

        // ---- P0: stage inputs; gamma_x; m halves; mask-sum ----
        {
            const int row = wid, f = lane;
            sh_x[row * 64 + f] = xv;
            sh_m[row * 64 + f] = mv;
            float gx = __expf(-fmaxf(dv * wdxf + bdxf, 0.0f));
            sh_gmbf[row * 136 + f] = __float2bfloat16(gx);
            bf16 mb = __float2bfloat16(mv);
            sh_gmbf[row * 136 + 64 + f] = mb;
            sh_inbf[row * 136 + 64 + f] = mb;
            sh_dbf[row * 72 + f] = __float2bfloat16(dv);
            float v0 = mv;
#pragma unroll
            for (int off = 32; off; off >>= 1) v0 += __shfl_xor(v0, off, 64);
            if (lane == 0) sh_msum[wid] = v0;
        }
        __syncthreads();  // bar A

        // ---- P1: gamma_h for OWN 64 cols; decay; stage slice ----
        if (wid < 4) {
            short8 a0 = *(const short8*)(sh_dbf + l16 * 72 + q * 8);
            short8 a1 = *(const short8*)(sh_dbf + l16 * 72 + 32 + q * 8);
            short8 w0 = *(const short8*)(lw_dh + colF * 72 + q * 8);
            short8 w1 = *(const short8*)(lw_dh + colF * 72 + 32 + q * 8);
            floatx4 acc = {0.f, 0.f, 0.f, 0.f};
            acc = MFMA16(a0, w0, acc);
            acc = MFMA16(a1, w1, acc);
#pragma unroll
            for (int r = 0; r < 4; ++r) {
                int row = q * 4 + r;
                float g = __expf(-fmaxf(acc[r] + bdl, 0.0f));
                bf16 hb = __float2bfloat16(sh_hloc[row * 66 + colF] * g);
                sh_hpub[row * 68 + colF] = hb;      // publish staging (own slice)
                sh_hbf[row * 264 + gcolH] = hb;     // own slice direct into full-h
            }
        }
        __syncthreads();  // bar B

        // ---- publish own 2KB slice: relaxed agent-scope atomic swaps (LLC) ----
        if (tid < 256) {
            int row = tid >> 4, c4 = (tid & 15) * 4;
            u64 v = *(const u64*)(sh_hpub + row * 68 + c4);
            __hip_atomic_exchange((u64*)(pubt + row * 256 + j * 64 + c4), v, __ATOMIC_RELAXED,
                                  __HIP_MEMORY_SCOPE_AGENT);
        }
        asm volatile("s_waitcnt vmcnt(0)" ::: "memory");
        __syncthreads();  // bar C: all swaps globally performed

        if (tid == 0) {
            __hip_atomic_fetch_add(cnt + grp, 1u, __ATOMIC_RELAXED, __HIP_MEMORY_SCOPE_AGENT);
            const unsigned int target = 4u * (unsigned int)(t + 1);
            while (__hip_atomic_fetch_add(cnt + grp, 0u, __ATOMIC_RELAXED,
                                          __HIP_MEMORY_SCOPE_AGENT) < target)
                __builtin_amdgcn_s_sleep(4);
        }
        __syncthreads();  // bar D: all siblings published step t

        // ---- read other siblings' slices (relaxed atomic reads at LLC) ----
        {
            int row = tid >> 6, lc = tid & 63;
            if ((lc >> 4) != j) {
                int c4 = lc * 4;
                u64 v = __hip_atomic_fetch_add((u64*)(pubt + row * 256 + c4), 0ull,
                                               __ATOMIC_RELAXED, __HIP_MEMORY_SCOPE_AGENT);
                *(u64*)(sh_hbf + row * 264 + c4) = v;
            }
        }
        __syncthreads();  // bar E: full decayed h resident

        // ---- P2: x_h = h@Whist^T + b (waves 0-3, LDS weights) ----
        float xh[4];
        float l1 = 0.f, l2 = 0.f, l3 = 0.f;
        if (wid < 4) {
            floatx4 acc = {0.f, 0.f, 0.f, 0.f};
#pragma unroll
            for (int kb = 0; kb < 8; ++kb) {
                short8 a = *(const short8*)(sh_hbf + l16 * 264 + kb * 32 + q * 8);
                short8 b = *(const short8*)(lw_hist + colF * 264 + kb * 32 + q * 8);
                acc = MFMA16(a, b, acc);
            }
#pragma unroll
            for (int r = 0; r < 4; ++r) {
                int row = q * 4 + r;
                xh[r] = acc[r] + bhl;
                float xx = sh_x[row * 64 + colF], mm = sh_m[row * 64 + colF];
                l1 += fabsf(xh[r] - xx) * mm;
                float xc = mm * xx + (1.0f - mm) * xh[r];
                sh_xcbf[row * 72 + colF] = __float2bfloat16(xc);
            }
        }
        __syncthreads();  // bar F

        // ---- P34: z_h, alpha, c_h, imputed (sibling 0 writes out), c_c ----
        if (wid < 4) {
            floatx4 accz = {0.f, 0.f, 0.f, 0.f};
            {
                short8 a = *(const short8*)(sh_xcbf + l16 * 72 + q * 8);
                accz = MFMA16(a, *(const short8*)(lw_feat + colF * 72 + q * 8), accz);
                a = *(const short8*)(sh_xcbf + l16 * 72 + 32 + q * 8);
                accz = MFMA16(a, *(const short8*)(lw_feat + colF * 72 + 32 + q * 8), accz);
            }
            floatx4 acca = {0.f, 0.f, 0.f, 0.f};
#pragma unroll
            for (int kb = 0; kb < 4; ++kb) {
                short8 a = *(const short8*)(sh_gmbf + l16 * 136 + kb * 32 + q * 8);
                short8 b = *(const short8*)(lw_comb + colF * 136 + kb * 32 + q * 8);
                acca = MFMA16(a, b, acca);
            }
#pragma unroll
            for (int r = 0; r < 4; ++r) {
                int row = q * 4 + r;
                float xx = sh_x[row * 64 + colF], mm = sh_m[row * 64 + colF];
                float z = accz[r] + bft;
                l2 += fabsf(z - xx) * mm;
                float al = sigmf(acca[r] + bcl);
                float ch = al * z + (1.0f - al) * xh[r];
                l3 += fabsf(ch - xx) * mm;
                float imp = mm * xx + (1.0f - mm) * ch;  // == c_c
                if (j == 0) out[((size_t)(b0 + row) * Tz + t) * Fz + colF] = imp;
                sh_inbf[row * 136 + colF] = __float2bfloat16(imp);
            }
            float v1 = l1, v2 = l2, v3 = l3;
#pragma unroll
            for (int off = 32; off; off >>= 1) {
                v1 += __shfl_xor(v1, off, 64);
                v2 += __shfl_xor(v2, off, 64);
                v3 += __shfl_xor(v3, off, 64);
            }
            if (lane == 0) {
                sh_lred[wid * 4 + 0] = v1;
                sh_lred[wid * 4 + 1] = v2;
                sh_lred[wid * 4 + 2] = v3;
            }
        }
        __syncthreads();  // bar G

        // ---- P5: gates slice from REGISTER weights (12 MFMAs/wave) ----
        {
            floatx4 acc = {0.f, 0.f, 0.f, 0.f};
#pragma unroll
            for (int s = 0; s < 12; ++s) {
                short8 a = (s < 4) ? *(const short8*)(sh_inbf + l16 * 136 + s * 32 + q * 8)
                                   : *(const short8*)(sh_hbf + l16 * 264 + (s - 4) * 32 + q * 8);
                acc = MFMA16(a, wfrag[s], acc);
            }
#pragma unroll
            for (int r = 0; r < 4; ++r) {
                float v = acc[r] + bgate;
                float tv = (gate == 2) ? tanhfast(v) : sigmf(v);
                sh_g[(gate * 16 + q * 4 + r) * 66 + ct * 16 + l16] = tv;
            }
        }
        __syncthreads();  // bar H

        // ---- LSTM elementwise; loss write; input prefetch ----
        {
            int row = tid >> 6, lcol = tid & 63;
            float Ig = sh_g[(0 * 16 + row) * 66 + lcol];
            float Fg = sh_g[(1 * 16 + row) * 66 + lcol];
            float Gg = sh_g[(2 * 16 + row) * 66 + lcol];
            float Og = sh_g[(3 * 16 + row) * 66 + lcol];
            creg = Fg * creg + Ig * Gg;
            sh_hloc[row * 66 + lcol] = Og * tanhfast(creg);
        }
        if (j == 0 && tid == 0) {
            float s0 = 0.0f;
#pragma unroll
            for (int i = 0; i < 16; ++i) s0 += sh_msum[i];
            float* lb = lossbuf + ((size_t)grp * Tz + t) * 4;
            lb[0] = s0;
            lb[1] = sh_lred[0] + sh_lred[4] + sh_lred[8] + sh_lred[12];
            lb[2] = sh_lred[1] + sh_lred[5] + sh_lred[9] + sh_lred[13];
            lb[3] = sh_lred[2] + sh_lred[6] + sh_lred[10] + sh_lred[14];
        }
        if (t + 1 < Tz) {
            size_t g = g0 + (size_t)(t + 1) * Fz;
            xv = X[g]; mv = Mm[g]; dv = Dd[g];
        }
        __syncthreads();  // bar I (sh_hloc/msum/lred safe for next step)
    }
}

__global__ void rits_finalize(const float* __restrict__ lossbuf, float* __restrict__ out) {
    __shared__ float m1[Tz], m2[Tz], m3[Tz];
    int t = threadIdx.x;
    if (t < Tz) {
        float s0 = 0.0f, s1 = 0.0f, s2 = 0.0f, s3 = 0.0f;
        for (int g = 0; g < GROUPS; ++g) {
            const float* lb = lossbuf + ((size_t)g * Tz + t) * 4;
            s0 += lb[0]; s1 += lb[1]; s2 += lb[2]; s3 += lb[3];
        }
        float inv = 1.0f / (s0 + 1e-9f);
        m1[t] = s1 * inv; m2[t] = s2 * inv; m3[t] = s3 * inv;
    }
    __syncthreads();
    if (t == 0) {
        float rm = 0.0f, rl = 0.0f;
        for (int i = 0; i < Tz; ++i) {  // literal replay of reference accumulation
            rl += m1[i]; rl += m2[i]; rm += m3[i]; rl += rm;
        }
        out[(size_t)Bz * Tz * Fz] = rm / (float)Tz;
        out[(size_t)Bz * Tz * Fz + 1] = rl / (3.0f * (float)Tz);
    }
}

extern "C" void kernel_launch(void* const* d_in, const int* in_sizes, int n_in,
                              void* d_out, int out_size, void* d_ws, size_t ws_size,
                              hipStream_t stream) {
    const float* X = (const float*)d_in[0];
    const float* Mm = (const float*)d_in[1];
    const float* Dd = (const float*)d_in[2];
    const float* Wdh = (const float*)d_in[3];
    const float* b_dh = (const float*)d_in[4];
    const float* Wdx = (const float*)d_in[5];
    const float* b_dx = (const float*)d_in[6];
    const float* Whist = (const float*)d_in[7];
    const float* b_hist = (const float*)d_in[8];
    const float* Wfeat = (const float*)d_in[9];
    const float* b_feat = (const float*)d_in[10];
    const float* Wcomb = (const float*)d_in[11];
    const float* b_comb = (const float*)d_in[12];
    const float* Wih = (const float*)d_in[13];
    const float* b_ih = (const float*)d_in[14];
    const float* Whh = (const float*)d_in[15];
    const float* b_hh = (const float*)d_in[16];
    float* out = (float*)d_out;

    bf16* wsbf = (bf16*)d_ws;
    float* wdxd = (float*)((char*)d_ws + 876544);
    float* lossbuf = (float*)((char*)d_ws + 876800);
    unsigned int* cnt = (unsigned int*)((char*)d_ws + 979200);
    bf16* pub = (bf16*)((char*)d_ws + 979456);

    rits_convert<<<1712, 256, 0, stream>>>(Wdh, Wdx, Whist, Wfeat, Wcomb, Wih, Whh, wsbf, wdxd,
                                           cnt);
    rits_main<<<GROUPS * SIBS, 1024, 0, stream>>>(
        X, Mm, Dd, b_dh, b_dx, b_hist, b_feat, b_comb, b_ih, b_hh, wsbf + 0, wsbf + 16384,
        wsbf + 32768, wsbf + 36864, wsbf + 45056, wdxd, lossbuf, cnt, pub, out);
    rits_finalize<<<1, 128, 0, stream>>>(lossbuf, out);
}

// Round 8
// 1155.922 us; speedup vs baseline: 9.7201x; 1.3241x over previous
//
#include <hip/hip_runtime.h>
#include <hip/hip_bf16.h>

// RITS recurrent imputation, B=1024 T=100 F=64 H=256.
// Round 8: R7 4-way N-split, sync rebuilt RMW-free:
//  - publish: one u64 relaxed agent atomic STORE per P1 lane (col-major pub,
//    no LDS transpose), per-wave padded flags after inline vmcnt(0)
//  - poll/readback: relaxed agent atomic LOADS (no RMW serialization/writeback)
//  - 7 barriers/step (was 9); alpha-GEMM on waves 4-7 in P1 window; waves
//    4-15 precompute P5 Whh+m slots during P2; out/loss writes rotated.

#define Bz 1024
#define Tz 100
#define Fz 64
#define Hz 256
#define GROUPS 64
#define SIBS 4
#define RPB 16

typedef __attribute__((ext_vector_type(8))) short short8;
typedef __attribute__((ext_vector_type(4))) float floatx4;
typedef __hip_bfloat16 bf16;
typedef unsigned long long u64;

#define MFMA16(a, b, c) __builtin_amdgcn_mfma_f32_16x16x32_bf16((a), (b), (c), 0, 0, 0)

__device__ __forceinline__ float sigmf(float x) { return 1.0f / (1.0f + __expf(-x)); }
__device__ __forceinline__ float tanhfast(float x) { return 2.0f / (1.0f + __expf(-2.0f * x)) - 1.0f; }

// ws layout (bytes):
//   wsbf (bf16): Wdh[256x64]@0, Whist[64x256]@16384, Wfeatm[64x64]@32768,
//     Wcomb[64x128]@36864, Wp5[12*32768]@45056 ; 438272 bf16 = 876544 B
//   @876544: wdx_diag[64] f32
//   @876800: lossbuf[64*100*4] f32 (102400 B)
//   @979200: flags[64*4*4] u32, stride 16B each (16384 B)
//   @995584: pub[64][2][256][4] u64 col-major (1 MB)
// Wp5 flat: s*32768 + w5*2048 + g*512 + l*32 + q*8 + e ; row n=g*256+w5*16+l.

__global__ void rits_convert(const float* __restrict__ Wdh, const float* __restrict__ Wdx,
                             const float* __restrict__ Whist, const float* __restrict__ Wfeat,
                             const float* __restrict__ Wcomb, const float* __restrict__ Wih,
                             const float* __restrict__ Whh, bf16* __restrict__ wsbf,
                             float* __restrict__ wdxd, unsigned int* __restrict__ flagsArr) {
    int idx = blockIdx.x * blockDim.x + threadIdx.x;
    if (idx < 4096) flagsArr[idx] = 0u;  // zero all flag lines each launch
    if (idx < 64) wdxd[idx] = Wdx[idx * 65];  // diag of W_dx
    if (idx >= 438272) return;
    float v;
    if (idx < 16384) v = Wdh[idx];
    else if (idx < 32768) v = Whist[idx - 16384];
    else if (idx < 36864) { int i = idx - 32768; v = ((i >> 6) == (i & 63)) ? 0.0f : Wfeat[i]; }
    else if (idx < 45056) v = Wcomb[idx - 36864];
    else {
        int i = idx - 45056;
        int e = i & 7, q = (i >> 3) & 3, l = (i >> 5) & 15, g = (i >> 9) & 3, w = (i >> 11) & 15;
        int s = i >> 15;
        int n = g * 256 + w * 16 + l;
        v = (s < 4) ? Wih[n * 128 + s * 32 + q * 8 + e] : Whh[n * 256 + (s - 4) * 32 + q * 8 + e];
    }
    wsbf[idx] = __float2bfloat16(v);
}

__global__ __launch_bounds__(1024, 4) void rits_main(
    const float* __restrict__ X, const float* __restrict__ Mm, const float* __restrict__ Dd,
    const float* __restrict__ b_dh, const float* __restrict__ b_dx,
    const float* __restrict__ b_hist, const float* __restrict__ b_feat,
    const float* __restrict__ b_comb, const float* __restrict__ b_ih,
    const float* __restrict__ b_hh,
    const bf16* __restrict__ Wdh, const bf16* __restrict__ Whist,
    const bf16* __restrict__ Wfeatm, const bf16* __restrict__ Wcomb,
    const bf16* __restrict__ Wp5,
    const float* __restrict__ wdxd, float* __restrict__ lossbuf,
    unsigned int* __restrict__ flags, u64* __restrict__ pub, float* __restrict__ out) {
    // ---- LDS (~125 KB -> 1 block/CU) ----
    __shared__ __align__(16) bf16 lw_hist[64 * 264];
    __shared__ __align__(16) bf16 lw_comb[64 * 136];
    __shared__ __align__(16) bf16 lw_feat[64 * 72];
    __shared__ __align__(16) bf16 lw_dh[64 * 72];
    __shared__ __align__(16) bf16 sh_hbf[RPB * 264];   // full decayed h (bf16)
    __shared__ __align__(16) float sh_x[RPB * 64];
    __shared__ __align__(16) float sh_m[RPB * 64];
    __shared__ __align__(16) bf16 sh_dbf[RPB * 72];
    __shared__ __align__(16) bf16 sh_xcbf[RPB * 72];
    __shared__ __align__(16) bf16 sh_gmbf[RPB * 136];
    __shared__ __align__(16) bf16 sh_inbf[RPB * 136];
    __shared__ __align__(16) float sh_alpha[RPB * 68];  // sigmoid(comb) from waves 4-7
    __shared__ __align__(16) float sh_g[4 * 16 * 66];   // post-nonlin gates (local cols)
    __shared__ __align__(16) float sh_hloc[16 * 66];    // fp32 h (local cols)
    __shared__ float sh_lred[16];
    __shared__ float sh_msum[16];

    const int tid = threadIdx.x;
    const int lane = tid & 63;
    const int wid = tid >> 6;   // 0..15
    const int l16 = lane & 15;
    const int q = lane >> 4;    // 0..3
    const int j = blockIdx.x & 3;     // sibling: owns H cols [64j, 64j+64)
    const int grp = blockIdx.x >> 2;  // group 0..63
    const int b0 = grp * RPB;

    // ---- one-time LDS copy-in of small weights ----
    for (int i = tid; i < 64 * 256; i += 1024) lw_hist[(i >> 8) * 264 + (i & 255)] = Whist[i];
    for (int i = tid; i < 64 * 128; i += 1024) lw_comb[(i >> 7) * 136 + (i & 127)] = Wcomb[i];
    for (int i = tid; i < 64 * 64; i += 1024) {
        lw_feat[(i >> 6) * 72 + (i & 63)] = Wfeatm[i];
        lw_dh[(i >> 6) * 72 + (i & 63)] = Wdh[(j * 64 + (i >> 6)) * 64 + (i & 63)];
    }
    for (int i = tid; i < 16 * 66; i += 1024) sh_hloc[i] = 0.0f;

    // ---- P5 gate-weight fragments: PERMANENT register residency ----
    const int gate = wid >> 2;  // 0..3 (i,f,g,o)
    const int ct = wid & 3;     // col-tile within sibling slice
    const int nrow = gate * 256 + j * 64 + ct * 16 + l16;
    short8 wfrag[12];
#pragma unroll
    for (int s = 0; s < 12; ++s)
        wfrag[s] = *(const short8*)(Wp5 + (size_t)s * 32768 + (j * 4 + ct) * 2048 + gate * 512 +
                                    l16 * 32 + q * 8);
    const float bgate = b_ih[nrow] + b_hh[nrow];

    // ---- step-invariant scalars ----
    const int colF = wid * 16 + l16;  // F col (waves 0-3)
    const int gcolH = j * 64 + colF;  // global H col (waves 0-3, P1)
    const float wdxf = wdxd[lane];
    const float bdxf = b_dx[lane];
    float bdl = 0.f, bhl = 0.f, bft = 0.f, bc2 = 0.f;
    if (wid < 4) { bdl = b_dh[gcolH]; bhl = b_hist[colF]; bft = b_feat[colF]; }
    if (wid >= 4 && wid < 8) bc2 = b_comb[(wid - 4) * 16 + l16];

    float creg = 0.0f;  // c state: element (row=tid>>6, lcol=tid&63)

    const size_t g0 = (size_t)(b0 + wid) * Tz * Fz + lane;
    float xv = X[g0], mv = Mm[g0], dv = Dd[g0];

    __syncthreads();

    for (int t = 0; t < Tz; ++t) {
        u64* pubt = pub + ((size_t)grp * 2 + (t & 1)) * 1024;  // [256 cols][4 q]

        // ---- P0: stage inputs; gamma_x; m halves; mask-sum ----
        {
            const int row = wid, f = lane;
            sh_x[row * 64 + f] = xv;
            sh_m[row * 64 + f] = mv;
            float gx = __expf(-fmaxf(dv * wdxf + bdxf, 0.0f));
            sh_gmbf[row * 136 + f] = __float2bfloat16(gx);
            bf16 mb = __float2bfloat16(mv);
            sh_gmbf[row * 136 + 64 + f] = mb;
            sh_inbf[row * 136 + 64 + f] = mb;
            sh_dbf[row * 72 + f] = __float2bfloat16(dv);
            float v0 = mv;
#pragma unroll
            for (int off = 32; off; off >>= 1) v0 += __shfl_xor(v0, off, 64);
            if (lane == 0) sh_msum[wid] = v0;
        }
        __syncthreads();  // bar A

        // ---- window A: P1+publish (w0-3) | alpha (w4-7) | m-slots (w8-15) ----
        floatx4 acc5 = {0.f, 0.f, 0.f, 0.f};  // P5 partial accumulator (w4-15)
        if (wid < 4) {
            short8 a0 = *(const short8*)(sh_dbf + l16 * 72 + q * 8);
            short8 a1 = *(const short8*)(sh_dbf + l16 * 72 + 32 + q * 8);
            short8 w0 = *(const short8*)(lw_dh + colF * 72 + q * 8);
            short8 w1 = *(const short8*)(lw_dh + colF * 72 + 32 + q * 8);
            floatx4 acc = {0.f, 0.f, 0.f, 0.f};
            acc = MFMA16(a0, w0, acc);
            acc = MFMA16(a1, w1, acc);
            u64 pk = 0;
#pragma unroll
            for (int r = 0; r < 4; ++r) {
                int row = q * 4 + r;
                float g = __expf(-fmaxf(acc[r] + bdl, 0.0f));
                bf16 hb = __float2bfloat16(sh_hloc[row * 66 + colF] * g);
                sh_hbf[row * 264 + gcolH] = hb;  // own slice direct into full-h
                pk |= (u64)(*(unsigned short*)&hb) << (16 * r);
            }
            __hip_atomic_store(pubt + (size_t)gcolH * 4 + q, pk, __ATOMIC_RELAXED,
                               __HIP_MEMORY_SCOPE_AGENT);
            asm volatile("s_waitcnt vmcnt(0)" ::: "memory");
            if (lane == 0)
                __hip_atomic_store(&flags[((grp * 4 + j) * 4 + wid) * 4], (unsigned)(t + 1),
                                   __ATOMIC_RELAXED, __HIP_MEMORY_SCOPE_AGENT);
        } else if (wid < 8) {
            floatx4 acca = {0.f, 0.f, 0.f, 0.f};
            const int ca = (wid - 4) * 16 + l16;
#pragma unroll
            for (int kb = 0; kb < 4; ++kb) {
                short8 a = *(const short8*)(sh_gmbf + l16 * 136 + kb * 32 + q * 8);
                short8 b = *(const short8*)(lw_comb + ca * 136 + kb * 32 + q * 8);
                acca = MFMA16(a, b, acca);
            }
#pragma unroll
            for (int r = 0; r < 4; ++r) sh_alpha[(q * 4 + r) * 68 + ca] = sigmf(acca[r] + bc2);
        } else {
#pragma unroll
            for (int s = 2; s < 4; ++s) {
                short8 a = *(const short8*)(sh_inbf + l16 * 136 + s * 32 + q * 8);
                acc5 = MFMA16(a, wfrag[s], acc5);
            }
        }
        // ---- poll remote flags (12 threads of wave 0) ----
        if (tid < 12) {
            int sidx = tid >> 2;
            int sib = sidx + (sidx >= j);
            int w = tid & 3;
            const unsigned target = (unsigned)(t + 1);
            unsigned it = 0;
            while (__hip_atomic_load(&flags[((grp * 4 + sib) * 4 + w) * 4], __ATOMIC_RELAXED,
                                     __HIP_MEMORY_SCOPE_AGENT) < target) {
                __builtin_amdgcn_s_sleep(1);
                if (++it > (1u << 23)) break;  // liveness escape
            }
        }
        __syncthreads();  // bar D: all remote slices published

        // ---- readback: 768 threads, 1 atomic u64 load each -> sh_hbf ----
        if (tid < 768) {
            int sidx = tid >> 8;               // 0..2
            int sib = sidx + (sidx >= j);
            int c = sib * 64 + ((tid >> 2) & 63);
            int qq = tid & 3;
            u64 v = __hip_atomic_load(pubt + (size_t)c * 4 + qq, __ATOMIC_RELAXED,
                                      __HIP_MEMORY_SCOPE_AGENT);
            unsigned short* hb = (unsigned short*)sh_hbf;
#pragma unroll
            for (int r = 0; r < 4; ++r) hb[(qq * 4 + r) * 264 + c] = (unsigned short)(v >> (16 * r));
        }
        __syncthreads();  // bar E: full decayed h resident

        // ---- window E: P2 (w0-3) | hh-slots (w4-15, +m for w4-7) ----
        float xh[4];
        float l1 = 0.f, l2 = 0.f, l3 = 0.f;
        if (wid < 4) {
            floatx4 acc = {0.f, 0.f, 0.f, 0.f};
#pragma unroll
            for (int kb = 0; kb < 8; ++kb) {
                short8 a = *(const short8*)(sh_hbf + l16 * 264 + kb * 32 + q * 8);
                short8 b = *(const short8*)(lw_hist + colF * 264 + kb * 32 + q * 8);
                acc = MFMA16(a, b, acc);
            }
#pragma unroll
            for (int r = 0; r < 4; ++r) {
                int row = q * 4 + r;
                xh[r] = acc[r] + bhl;
                float xx = sh_x[row * 64 + colF], mm = sh_m[row * 64 + colF];
                l1 += fabsf(xh[r] - xx) * mm;
                float xc = mm * xx + (1.0f - mm) * xh[r];
                sh_xcbf[row * 72 + colF] = __float2bfloat16(xc);
            }
        } else {
            if (wid < 8) {
#pragma unroll
                for (int s = 2; s < 4; ++s) {
                    short8 a = *(const short8*)(sh_inbf + l16 * 136 + s * 32 + q * 8);
                    acc5 = MFMA16(a, wfrag[s], acc5);
                }
            }
#pragma unroll
            for (int s = 4; s < 12; ++s) {
                short8 a = *(const short8*)(sh_hbf + l16 * 264 + (s - 4) * 32 + q * 8);
                acc5 = MFMA16(a, wfrag[s], acc5);
            }
        }
        __syncthreads();  // bar F

        // ---- window F: z_h + combine + epilogue (w0-3 only) ----
        if (wid < 4) {
            floatx4 accz = {0.f, 0.f, 0.f, 0.f};
            {
                short8 a = *(const short8*)(sh_xcbf + l16 * 72 + q * 8);
                accz = MFMA16(a, *(const short8*)(lw_feat + colF * 72 + q * 8), accz);
                a = *(const short8*)(sh_xcbf + l16 * 72 + 32 + q * 8);
                accz = MFMA16(a, *(const short8*)(lw_feat + colF * 72 + 32 + q * 8), accz);
            }
#pragma unroll
            for (int r = 0; r < 4; ++r) {
                int row = q * 4 + r;
                float xx = sh_x[row * 64 + colF], mm = sh_m[row * 64 + colF];
                float z = accz[r] + bft;
                l2 += fabsf(z - xx) * mm;
                float al = sh_alpha[row * 68 + colF];
                float ch = al * z + (1.0f - al) * xh[r];
                l3 += fabsf(ch - xx) * mm;
                float imp = mm * xx + (1.0f - mm) * ch;  // == c_c
                if (wid == j) out[((size_t)(b0 + row) * Tz + t) * Fz + colF] = imp;
                sh_inbf[row * 136 + colF] = __float2bfloat16(imp);
            }
            float v1 = l1, v2 = l2, v3 = l3;
#pragma unroll
            for (int off = 32; off; off >>= 1) {
                v1 += __shfl_xor(v1, off, 64);
                v2 += __shfl_xor(v2, off, 64);
                v3 += __shfl_xor(v3, off, 64);
            }
            if (lane == 0) {
                sh_lred[wid * 4 + 0] = v1;
                sh_lred[wid * 4 + 1] = v2;
                sh_lred[wid * 4 + 2] = v3;
            }
        }
        __syncthreads();  // bar G

        // ---- window G: finish gates. w0-3: all 12 slots; w4-15: c_c slots ----
        {
            if (wid < 4) {
#pragma unroll
                for (int s = 0; s < 12; ++s) {
                    short8 a = (s < 4) ? *(const short8*)(sh_inbf + l16 * 136 + s * 32 + q * 8)
                                       : *(const short8*)(sh_hbf + l16 * 264 + (s - 4) * 32 + q * 8);
                    acc5 = MFMA16(a, wfrag[s], acc5);
                }
            } else {
#pragma unroll
                for (int s = 0; s < 2; ++s) {
                    short8 a = *(const short8*)(sh_inbf + l16 * 136 + s * 32 + q * 8);
                    acc5 = MFMA16(a, wfrag[s], acc5);
                }
            }
#pragma unroll
            for (int r = 0; r < 4; ++r) {
                float v = acc5[r] + bgate;
                float tv = (gate == 2) ? tanhfast(v) : sigmf(v);
                sh_g[(gate * 16 + q * 4 + r) * 66 + ct * 16 + l16] = tv;
            }
        }
        __syncthreads();  // bar H

        // ---- LSTM elementwise; loss write (rotating sibling); prefetch ----
        {
            int row = tid >> 6, lcol = tid & 63;
            float Ig = sh_g[(0 * 16 + row) * 66 + lcol];
            float Fg = sh_g[(1 * 16 + row) * 66 + lcol];
            float Gg = sh_g[(2 * 16 + row) * 66 + lcol];
            float Og = sh_g[(3 * 16 + row) * 66 + lcol];
            creg = Fg * creg + Ig * Gg;
            sh_hloc[row * 66 + lcol] = Og * tanhfast(creg);
        }
        if (((t & 3) == j) && tid == 0) {
            float s0 = 0.0f;
#pragma unroll
            for (int i = 0; i < 16; ++i) s0 += sh_msum[i];
            float* lb = lossbuf + ((size_t)grp * Tz + t) * 4;
            lb[0] = s0;
            lb[1] = sh_lred[0] + sh_lred[4] + sh_lred[8] + sh_lred[12];
            lb[2] = sh_lred[1] + sh_lred[5] + sh_lred[9] + sh_lred[13];
            lb[3] = sh_lred[2] + sh_lred[6] + sh_lred[10] + sh_lred[14];
        }
        if (t + 1 < Tz) {
            size_t g = g0 + (size_t)(t + 1) * Fz;
            xv = X[g]; mv = Mm[g]; dv = Dd[g];
        }
        __syncthreads();  // bar I (sh_hloc/msum/lred safe for next step)
    }
}

__global__ void rits_finalize(const float* __restrict__ lossbuf, float* __restrict__ out) {
    __shared__ float m1[Tz], m2[Tz], m3[Tz];
    int t = threadIdx.x;
    if (t < Tz) {
        float s0 = 0.0f, s1 = 0.0f, s2 = 0.0f, s3 = 0.0f;
        for (int g = 0; g < GROUPS; ++g) {
            const float* lb = lossbuf + ((size_t)g * Tz + t) * 4;
            s0 += lb[0]; s1 += lb[1]; s2 += lb[2]; s3 += lb[3];
        }
        float inv = 1.0f / (s0 + 1e-9f);
        m1[t] = s1 * inv; m2[t] = s2 * inv; m3[t] = s3 * inv;
    }
    __syncthreads();
    if (t == 0) {
        float rm = 0.0f, rl = 0.0f;
        for (int i = 0; i < Tz; ++i) {  // literal replay of reference accumulation
            rl += m1[i]; rl += m2[i]; rm += m3[i]; rl += rm;
        }
        out[(size_t)Bz * Tz * Fz] = rm / (float)Tz;
        out[(size_t)Bz * Tz * Fz + 1] = rl / (3.0f * (float)Tz);
    }
}

extern "C" void kernel_launch(void* const* d_in, const int* in_sizes, int n_in,
                              void* d_out, int out_size, void* d_ws, size_t ws_size,
                              hipStream_t stream) {
    const float* X = (const float*)d_in[0];
    const float* Mm = (const float*)d_in[1];
    const float* Dd = (const float*)d_in[2];
    const float* Wdh = (const float*)d_in[3];
    const float* b_dh = (const float*)d_in[4];
    const float* Wdx = (const float*)d_in[5];
    const float* b_dx = (const float*)d_in[6];
    const float* Whist = (const float*)d_in[7];
    const float* b_hist = (const float*)d_in[8];
    const float* Wfeat = (const float*)d_in[9];
    const float* b_feat = (const float*)d_in[10];
    const float* Wcomb = (const float*)d_in[11];
    const float* b_comb = (const float*)d_in[12];
    const float* Wih = (const float*)d_in[13];
    const float* b_ih = (const float*)d_in[14];
    const float* Whh = (const float*)d_in[15];
    const float* b_hh = (const float*)d_in[16];
    float* out = (float*)d_out;

    bf16* wsbf = (bf16*)d_ws;
    float* wdxd = (float*)((char*)d_ws + 876544);
    float* lossbuf = (float*)((char*)d_ws + 876800);
    unsigned int* flags = (unsigned int*)((char*)d_ws + 979200);
    u64* pub = (u64*)((char*)d_ws + 995584);

    rits_convert<<<1712, 256, 0, stream>>>(Wdh, Wdx, Whist, Wfeat, Wcomb, Wih, Whh, wsbf, wdxd,
                                           flags);
    rits_main<<<GROUPS * SIBS, 1024, 0, stream>>>(
        X, Mm, Dd, b_dh, b_dx, b_hist, b_feat, b_comb, b_ih, b_hh, wsbf + 0, wsbf + 16384,
        wsbf + 32768, wsbf + 36864, wsbf + 45056, wdxd, lossbuf, flags, pub, out);
    rits_finalize<<<1, 128, 0, stream>>>(lossbuf, out);
}

// Round 9
// 963.351 us; speedup vs baseline: 11.6631x; 1.1999x over previous
//
#include <hip/hip_runtime.h>
#include <hip/hip_bf16.h>

// RITS recurrent imputation, B=1024 T=100 F=64 H=256.
// Round 9: exchange OFF the critical path. gamma_h(d_{t+1}) is computed in
// step t (d prefetched), so decayed-h publish fuses into step t's LSTM
// elementwise tail. Poll at t+1 head is then ~1-shot (flags a full step old).
// Rebalance: w4-7 own P2->P34; all 16 waves own one gate tile (h/m-slots in
// the P2 window; only 2 c_c-slots after the epilogue). c-state in LDS so 256
// threads do update+pack+publish straight from registers. 6 barriers/step.

#define Bz 1024
#define Tz 100
#define Fz 64
#define Hz 256
#define GROUPS 64
#define SIBS 4
#define RPB 16

typedef __attribute__((ext_vector_type(8))) short short8;
typedef __attribute__((ext_vector_type(4))) float floatx4;
typedef __hip_bfloat16 bf16;
typedef unsigned long long u64;

#define MFMA16(a, b, c) __builtin_amdgcn_mfma_f32_16x16x32_bf16((a), (b), (c), 0, 0, 0)

__device__ __forceinline__ float sigmf(float x) { return 1.0f / (1.0f + __expf(-x)); }
__device__ __forceinline__ float tanhfast(float x) { return 2.0f / (1.0f + __expf(-2.0f * x)) - 1.0f; }

// ws layout (bytes):
//   wsbf (bf16): Wdh[256x64]@0, Whist[64x256]@16384, Wfeatm[64x64]@32768,
//     Wcomb[64x128]@36864, Wp5[12*32768]@45056 ; 438272 bf16 = 876544 B
//   @876544: wdx_diag[64] f32
//   @876800: lossbuf[64*100*4] f32 (102400 B)
//   @979200: flags[64*4*4] u32, stride 16B each (16384 B)
//   @995584: pub[64][2][256][4] u64 (1 MB)
// Wp5 flat: s*32768 + w5*2048 + g*512 + l*32 + q*8 + e ; row n=g*256+w5*16+l.

__global__ void rits_convert(const float* __restrict__ Wdh, const float* __restrict__ Wdx,
                             const float* __restrict__ Whist, const float* __restrict__ Wfeat,
                             const float* __restrict__ Wcomb, const float* __restrict__ Wih,
                             const float* __restrict__ Whh, bf16* __restrict__ wsbf,
                             float* __restrict__ wdxd, unsigned int* __restrict__ flagsArr) {
    int idx = blockIdx.x * blockDim.x + threadIdx.x;
    if (idx < 4096) flagsArr[idx] = 0u;  // zero all flag lines each launch
    if (idx < 64) wdxd[idx] = Wdx[idx * 65];  // diag of W_dx
    if (idx >= 438272) return;
    float v;
    if (idx < 16384) v = Wdh[idx];
    else if (idx < 32768) v = Whist[idx - 16384];
    else if (idx < 36864) { int i = idx - 32768; v = ((i >> 6) == (i & 63)) ? 0.0f : Wfeat[i]; }
    else if (idx < 45056) v = Wcomb[idx - 36864];
    else {
        int i = idx - 45056;
        int e = i & 7, q = (i >> 3) & 3, l = (i >> 5) & 15, g = (i >> 9) & 3, w = (i >> 11) & 15;
        int s = i >> 15;
        int n = g * 256 + w * 16 + l;
        v = (s < 4) ? Wih[n * 128 + s * 32 + q * 8 + e] : Whh[n * 256 + (s - 4) * 32 + q * 8 + e];
    }
    wsbf[idx] = __float2bfloat16(v);
}

__global__ __launch_bounds__(1024, 4) void rits_main(
    const float* __restrict__ X, const float* __restrict__ Mm, const float* __restrict__ Dd,
    const float* __restrict__ b_dh, const float* __restrict__ b_dx,
    const float* __restrict__ b_hist, const float* __restrict__ b_feat,
    const float* __restrict__ b_comb, const float* __restrict__ b_ih,
    const float* __restrict__ b_hh,
    const bf16* __restrict__ Wdh, const bf16* __restrict__ Whist,
    const bf16* __restrict__ Wfeatm, const bf16* __restrict__ Wcomb,
    const bf16* __restrict__ Wp5,
    const float* __restrict__ wdxd, float* __restrict__ lossbuf,
    unsigned int* __restrict__ flags, u64* __restrict__ pub, float* __restrict__ out) {
    // ---- LDS (~130 KB -> 1 block/CU) ----
    __shared__ __align__(16) bf16 lw_hist[64 * 264];
    __shared__ __align__(16) bf16 lw_comb[64 * 136];
    __shared__ __align__(16) bf16 lw_feat[64 * 72];
    __shared__ __align__(16) bf16 lw_dh[64 * 72];
    __shared__ __align__(16) bf16 sh_hbf[RPB * 264];   // full decayed h (bf16)
    __shared__ __align__(16) float sh_x[RPB * 64];
    __shared__ __align__(16) float sh_m[RPB * 64];
    __shared__ __align__(16) bf16 sh_dbf2[RPB * 72];   // d(t+1), staged in W2
    __shared__ __align__(16) bf16 sh_xcbf[RPB * 72];
    __shared__ __align__(16) bf16 sh_gmbf[RPB * 136];
    __shared__ __align__(16) bf16 sh_inbf[RPB * 136];
    __shared__ __align__(16) float sh_alpha[RPB * 68];
    __shared__ __align__(16) float sh_gam[RPB * 68];   // gamma_h(d_{t+1}), own cols
    __shared__ __align__(16) float sh_g[4 * 16 * 66];  // post-nonlin gates
    __shared__ __align__(16) float sh_c[64 * 16];      // c state, col-major [col][row]
    __shared__ float sh_lred[16];
    __shared__ float sh_msum[16];

    const int tid = threadIdx.x;
    const int lane = tid & 63;
    const int wid = tid >> 6;   // 0..15
    const int l16 = lane & 15;
    const int q = lane >> 4;    // 0..3
    const int j = blockIdx.x & 3;     // sibling: owns H cols [64j, 64j+64)
    const int grp = blockIdx.x >> 2;  // group 0..63
    const int b0 = grp * RPB;

    // ---- one-time LDS copy-in of small weights; state init ----
    for (int i = tid; i < 64 * 256; i += 1024) lw_hist[(i >> 8) * 264 + (i & 255)] = Whist[i];
    for (int i = tid; i < 64 * 128; i += 1024) lw_comb[(i >> 7) * 136 + (i & 127)] = Wcomb[i];
    for (int i = tid; i < 64 * 64; i += 1024) {
        lw_feat[(i >> 6) * 72 + (i & 63)] = Wfeatm[i];
        lw_dh[(i >> 6) * 72 + (i & 63)] = Wdh[(j * 64 + (i >> 6)) * 64 + (i & 63)];
    }
    for (int i = tid; i < 64 * 16; i += 1024) sh_c[i] = 0.0f;
    for (int i = tid; i < RPB * 264; i += 1024) sh_hbf[i] = (bf16)0.0f;

    // ---- P5 gate-weight fragments: PERMANENT register residency ----
    const int gate = wid >> 2;  // 0..3 (i,f,g,o)
    const int ct = wid & 3;     // col-tile within sibling slice
    const int nrow = gate * 256 + j * 64 + ct * 16 + l16;
    short8 wfrag[12];
#pragma unroll
    for (int s = 0; s < 12; ++s)
        wfrag[s] = *(const short8*)(Wp5 + (size_t)s * 32768 + (j * 4 + ct) * 2048 + gate * 512 +
                                    l16 * 32 + q * 8);
    const float bgate = b_ih[nrow] + b_hh[nrow];

    // ---- step-invariant scalars (per-role) ----
    const float wdxf = wdxd[lane];
    const float bdxf = b_dx[lane];
    const int ca = wid * 16 + l16;          // alpha col (w0-3)
    const int colF = (wid - 4) * 16 + l16;  // F col (w4-7)
    const int colg = (wid - 8) * 16 + l16;  // gamma2 local col (w8-11)
    float bc2 = 0.f, bhl = 0.f, bft = 0.f, bdl = 0.f;
    if (wid < 4) bc2 = b_comb[ca];
    else if (wid < 8) { bhl = b_hist[colF]; bft = b_feat[colF]; }
    else if (wid < 12) bdl = b_dh[j * 64 + colg];

    const size_t g0 = (size_t)(b0 + wid) * Tz * Fz + lane;
    float xv = X[g0], mv = Mm[g0], dv = Dd[g0];

    __syncthreads();

    // ---- initial publish: zeros for t=0 (h=0 -> decayed h=0), flags=1 ----
    {
        u64* pub0 = pub + (size_t)grp * 2 * 1024;
        if (tid < 256) {
            int col = tid >> 2, qq = tid & 3;
            __hip_atomic_store(pub0 + (size_t)(j * 64 + col) * 4 + qq, 0ull, __ATOMIC_RELAXED,
                               __HIP_MEMORY_SCOPE_AGENT);
        }
        asm volatile("s_waitcnt vmcnt(0)" ::: "memory");
        if (tid < 256 && lane == 0)
            __hip_atomic_store(&flags[((grp * 4 + j) * 4 + wid) * 4], 1u, __ATOMIC_RELAXED,
                               __HIP_MEMORY_SCOPE_AGENT);
    }

    for (int t = 0; t < Tz; ++t) {
        u64* pubt = pub + ((size_t)grp * 2 + (t & 1)) * 1024;

        // ---- W0: stage x,m; gamma_x; msum; issue t+1 prefetch; poll ----
        {
            const int row = wid, f = lane;
            sh_x[row * 64 + f] = xv;
            sh_m[row * 64 + f] = mv;
            float gx = __expf(-fmaxf(dv * wdxf + bdxf, 0.0f));
            sh_gmbf[row * 136 + f] = __float2bfloat16(gx);
            bf16 mb = __float2bfloat16(mv);
            sh_gmbf[row * 136 + 64 + f] = mb;
            sh_inbf[row * 136 + 64 + f] = mb;
            float v0 = mv;
#pragma unroll
            for (int off = 32; off; off >>= 1) v0 += __shfl_xor(v0, off, 64);
            if (lane == 0) sh_msum[wid] = v0;
        }
        if (t + 1 < Tz) {  // regs now hold t+1 (dv consumed by gamma_x above)
            size_t g = g0 + (size_t)(t + 1) * Fz;
            xv = X[g]; mv = Mm[g]; dv = Dd[g];
        }
        if (tid < 12) {  // flags were set during remote step t-1 tail -> ~1-shot
            int sidx = tid >> 2;
            int sib = sidx + (sidx >= j);
            int w = tid & 3;
            const unsigned target = (unsigned)(t + 1);
            unsigned it = 0;
            while (__hip_atomic_load(&flags[((grp * 4 + sib) * 4 + w) * 4], __ATOMIC_RELAXED,
                                     __HIP_MEMORY_SCOPE_AGENT) < target) {
                __builtin_amdgcn_s_sleep(1);
                if (++it > (1u << 22)) break;  // liveness escape
            }
        }
        __syncthreads();  // bar1

        // ---- W1: readback remote decayed-h slices -> sh_hbf ----
        if (tid < 768) {
            int sidx = tid >> 8;
            int sib = sidx + (sidx >= j);
            int c = sib * 64 + ((tid >> 2) & 63);
            int qq = tid & 3;
            u64 v = __hip_atomic_load(pubt + (size_t)c * 4 + qq, __ATOMIC_RELAXED,
                                      __HIP_MEMORY_SCOPE_AGENT);
            unsigned short* hb = (unsigned short*)sh_hbf;
#pragma unroll
            for (int r = 0; r < 4; ++r) hb[(qq * 4 + r) * 264 + c] = (unsigned short)(v >> (16 * r));
        }
        __syncthreads();  // bar2

        // ---- W2: P2+xc (w4-7) | alpha (w0-3) | P5 s2-11 (all but w4-7) ----
        floatx4 acc5 = {0.f, 0.f, 0.f, 0.f};
        float xh[4];
        float l1 = 0.f, l2 = 0.f, l3 = 0.f;
        if (wid >= 4 && wid < 8) {
            floatx4 acc = {0.f, 0.f, 0.f, 0.f};
#pragma unroll
            for (int kb = 0; kb < 8; ++kb) {
                short8 a = *(const short8*)(sh_hbf + l16 * 264 + kb * 32 + q * 8);
                short8 b = *(const short8*)(lw_hist + colF * 264 + kb * 32 + q * 8);
                acc = MFMA16(a, b, acc);
            }
#pragma unroll
            for (int r = 0; r < 4; ++r) {
                int row = q * 4 + r;
                xh[r] = acc[r] + bhl;
                float xx = sh_x[row * 64 + colF], mm = sh_m[row * 64 + colF];
                l1 += fabsf(xh[r] - xx) * mm;
                float xc = mm * xx + (1.0f - mm) * xh[r];
                sh_xcbf[row * 72 + colF] = __float2bfloat16(xc);
            }
        } else {
            if (wid < 4) {
                floatx4 acca = {0.f, 0.f, 0.f, 0.f};
#pragma unroll
                for (int kb = 0; kb < 4; ++kb) {
                    short8 a = *(const short8*)(sh_gmbf + l16 * 136 + kb * 32 + q * 8);
                    short8 b = *(const short8*)(lw_comb + ca * 136 + kb * 32 + q * 8);
                    acca = MFMA16(a, b, acca);
                }
#pragma unroll
                for (int r = 0; r < 4; ++r) sh_alpha[(q * 4 + r) * 68 + ca] = sigmf(acca[r] + bc2);
            }
#pragma unroll
            for (int s = 2; s < 4; ++s) {
                short8 a = *(const short8*)(sh_inbf + l16 * 136 + s * 32 + q * 8);
                acc5 = MFMA16(a, wfrag[s], acc5);
            }
#pragma unroll
            for (int s = 4; s < 12; ++s) {
                short8 a = *(const short8*)(sh_hbf + l16 * 264 + (s - 4) * 32 + q * 8);
                acc5 = MFMA16(a, wfrag[s], acc5);
            }
        }
        if (t + 1 < Tz) sh_dbf2[wid * 72 + lane] = __float2bfloat16(dv);
        __syncthreads();  // bar3

        // ---- W3: P34 epilogue (w4-7) | gamma_h(d_{t+1}) (w8-11) ----
        if (wid >= 4 && wid < 8) {
            floatx4 accz = {0.f, 0.f, 0.f, 0.f};
            {
                short8 a = *(const short8*)(sh_xcbf + l16 * 72 + q * 8);
                accz = MFMA16(a, *(const short8*)(lw_feat + colF * 72 + q * 8), accz);
                a = *(const short8*)(sh_xcbf + l16 * 72 + 32 + q * 8);
                accz = MFMA16(a, *(const short8*)(lw_feat + colF * 72 + 32 + q * 8), accz);
            }
#pragma unroll
            for (int r = 0; r < 4; ++r) {
                int row = q * 4 + r;
                float xx = sh_x[row * 64 + colF], mm = sh_m[row * 64 + colF];
                float z = accz[r] + bft;
                l2 += fabsf(z - xx) * mm;
                float al = sh_alpha[row * 68 + colF];
                float ch = al * z + (1.0f - al) * xh[r];
                l3 += fabsf(ch - xx) * mm;
                float imp = mm * xx + (1.0f - mm) * ch;  // == c_c
                if (wid - 4 == j) out[((size_t)(b0 + row) * Tz + t) * Fz + colF] = imp;
                sh_inbf[row * 136 + colF] = __float2bfloat16(imp);
            }
            float v1 = l1, v2 = l2, v3 = l3;
#pragma unroll
            for (int off = 32; off; off >>= 1) {
                v1 += __shfl_xor(v1, off, 64);
                v2 += __shfl_xor(v2, off, 64);
                v3 += __shfl_xor(v3, off, 64);
            }
            if (lane == 0) {
                sh_lred[(wid - 4) * 4 + 0] = v1;
                sh_lred[(wid - 4) * 4 + 1] = v2;
                sh_lred[(wid - 4) * 4 + 2] = v3;
            }
        } else if (wid >= 8 && wid < 12 && t + 1 < Tz) {
            short8 a0 = *(const short8*)(sh_dbf2 + l16 * 72 + q * 8);
            short8 a1 = *(const short8*)(sh_dbf2 + l16 * 72 + 32 + q * 8);
            short8 w0 = *(const short8*)(lw_dh + colg * 72 + q * 8);
            short8 w1 = *(const short8*)(lw_dh + colg * 72 + 32 + q * 8);
            floatx4 acc = {0.f, 0.f, 0.f, 0.f};
            acc = MFMA16(a0, w0, acc);
            acc = MFMA16(a1, w1, acc);
#pragma unroll
            for (int r = 0; r < 4; ++r)
                sh_gam[(q * 4 + r) * 68 + colg] = __expf(-fmaxf(acc[r] + bdl, 0.0f));
        }
        __syncthreads();  // bar4

        // ---- W4: all 16 waves finish gates (s0,1 = c_c slots) + nonlin ----
        {
#pragma unroll
            for (int s = 0; s < 2; ++s) {
                short8 a = *(const short8*)(sh_inbf + l16 * 136 + s * 32 + q * 8);
                acc5 = MFMA16(a, wfrag[s], acc5);
            }
#pragma unroll
            for (int r = 0; r < 4; ++r) {
                float v = acc5[r] + bgate;
                float tv = (gate == 2) ? tanhfast(v) : sigmf(v);
                sh_g[(gate * 16 + q * 4 + r) * 66 + ct * 16 + l16] = tv;
            }
        }
        __syncthreads();  // bar5

        // ---- W5: LSTM update + decay + publish (256 thr, 4 rows each) ----
        if (tid < 256) {
            int col = tid >> 2, q2 = tid & 3;
            int gcol = j * 64 + col;
            float4 cv = *(float4*)(sh_c + col * 16 + q2 * 4);
            float cc[4] = {cv.x, cv.y, cv.z, cv.w};
            u64 pk = 0;
#pragma unroll
            for (int r = 0; r < 4; ++r) {
                int row = q2 * 4 + r;
                float Ig = sh_g[(0 * 16 + row) * 66 + col];
                float Fg = sh_g[(1 * 16 + row) * 66 + col];
                float Gg = sh_g[(2 * 16 + row) * 66 + col];
                float Og = sh_g[(3 * 16 + row) * 66 + col];
                float c = Fg * cc[r] + Ig * Gg;
                cc[r] = c;
                if (t + 1 < Tz) {
                    float h = Og * tanhfast(c);
                    float hd = h * sh_gam[row * 68 + col];
                    bf16 hb = __float2bfloat16(hd);
                    sh_hbf[row * 264 + gcol] = hb;  // own slice for next step
                    pk |= (u64)(*(unsigned short*)&hb) << (16 * r);
                }
            }
            *(float4*)(sh_c + col * 16 + q2 * 4) = (float4){cc[0], cc[1], cc[2], cc[3]};
            if (t + 1 < Tz) {
                u64* pubn = pub + ((size_t)grp * 2 + ((t + 1) & 1)) * 1024;
                __hip_atomic_store(pubn + (size_t)gcol * 4 + q2, pk, __ATOMIC_RELAXED,
                                   __HIP_MEMORY_SCOPE_AGENT);
            }
        }
        if (tid < 256 && t + 1 < Tz) {
            asm volatile("s_waitcnt vmcnt(0)" ::: "memory");
            if (lane == 0)
                __hip_atomic_store(&flags[((grp * 4 + j) * 4 + wid) * 4], (unsigned)(t + 2),
                                   __ATOMIC_RELAXED, __HIP_MEMORY_SCOPE_AGENT);
        }
        if (tid == 256 && ((t & 3) == j)) {
            float s0 = 0.0f;
#pragma unroll
            for (int i = 0; i < 16; ++i) s0 += sh_msum[i];
            float* lb = lossbuf + ((size_t)grp * Tz + t) * 4;
            lb[0] = s0;
            lb[1] = sh_lred[0] + sh_lred[4] + sh_lred[8] + sh_lred[12];
            lb[2] = sh_lred[1] + sh_lred[5] + sh_lred[9] + sh_lred[13];
            lb[3] = sh_lred[2] + sh_lred[6] + sh_lred[10] + sh_lred[14];
        }
        __syncthreads();  // bar6 (protects all sh_* for next step)
    }
}

__global__ void rits_finalize(const float* __restrict__ lossbuf, float* __restrict__ out) {
    __shared__ float m1[Tz], m2[Tz], m3[Tz];
    int t = threadIdx.x;
    if (t < Tz) {
        float s0 = 0.0f, s1 = 0.0f, s2 = 0.0f, s3 = 0.0f;
        for (int g = 0; g < GROUPS; ++g) {
            const float* lb = lossbuf + ((size_t)g * Tz + t) * 4;
            s0 += lb[0]; s1 += lb[1]; s2 += lb[2]; s3 += lb[3];
        }
        float inv = 1.0f / (s0 + 1e-9f);
        m1[t] = s1 * inv; m2[t] = s2 * inv; m3[t] = s3 * inv;
    }
    __syncthreads();
    if (t == 0) {
        float rm = 0.0f, rl = 0.0f;
        for (int i = 0; i < Tz; ++i) {  // literal replay of reference accumulation
            rl += m1[i]; rl += m2[i]; rm += m3[i]; rl += rm;
        }
        out[(size_t)Bz * Tz * Fz] = rm / (float)Tz;
        out[(size_t)Bz * Tz * Fz + 1] = rl / (3.0f * (float)Tz);
    }
}

extern "C" void kernel_launch(void* const* d_in, const int* in_sizes, int n_in,
                              void* d_out, int out_size, void* d_ws, size_t ws_size,
                              hipStream_t stream) {
    const float* X = (const float*)d_in[0];
    const float* Mm = (const float*)d_in[1];
    const float* Dd = (const float*)d_in[2];
    const float* Wdh = (const float*)d_in[3];
    const float* b_dh = (const float*)d_in[4];
    const float* Wdx = (const float*)d_in[5];
    const float* b_dx = (const float*)d_in[6];
    const float* Whist = (const float*)d_in[7];
    const float* b_hist = (const float*)d_in[8];
    const float* Wfeat = (const float*)d_in[9];
    const float* b_feat = (const float*)d_in[10];
    const float* Wcomb = (const float*)d_in[11];
    const float* b_comb = (const float*)d_in[12];
    const float* Wih = (const float*)d_in[13];
    const float* b_ih = (const float*)d_in[14];
    const float* Whh = (const float*)d_in[15];
    const float* b_hh = (const float*)d_in[16];
    float* out = (float*)d_out;

    bf16* wsbf = (bf16*)d_ws;
    float* wdxd = (float*)((char*)d_ws + 876544);
    float* lossbuf = (float*)((char*)d_ws + 876800);
    unsigned int* flags = (unsigned int*)((char*)d_ws + 979200);
    u64* pub = (u64*)((char*)d_ws + 995584);

    rits_convert<<<1712, 256, 0, stream>>>(Wdh, Wdx, Whist, Wfeat, Wcomb, Wih, Whh, wsbf, wdxd,
                                           flags);
    rits_main<<<GROUPS * SIBS, 1024, 0, stream>>>(
        X, Mm, Dd, b_dh, b_dx, b_hist, b_feat, b_comb, b_ih, b_hh, wsbf + 0, wsbf + 16384,
        wsbf + 32768, wsbf + 36864, wsbf + 45056, wdxd, lossbuf, flags, pub, out);
    rits_finalize<<<1, 128, 0, stream>>>(lossbuf, out);
}